// Round 13
// baseline (57.836 us; speedup 1.0000x reference)
//
#include <hip/hip_runtime.h>

#define DEV __device__ __forceinline__

typedef __attribute__((ext_vector_type(4))) float f32x4;
typedef __bf16 bf16_t;
typedef __attribute__((ext_vector_type(4))) bf16_t bf16x4;
typedef __attribute__((ext_vector_type(8))) bf16_t bf16x8;
typedef __attribute__((ext_vector_type(8))) unsigned short us8;
typedef __attribute__((ext_vector_type(4))) unsigned short us4;

// B=8, S=2048, D_MODEL=256, H=4, DEPTH=64, BH=32, M=B*S=16384

DEV unsigned short f2bf(float f) {
  bf16_t h = (bf16_t)f;
  return __builtin_bit_cast(unsigned short, h);
}

DEV void gl2lds16(const void* g, void* l) {
  __builtin_amdgcn_global_load_lds(
      (const __attribute__((address_space(1))) unsigned int*)g,
      (__attribute__((address_space(3))) unsigned int*)l, 16, 0, 0);
}

DEV f32x4 mfma16(bf16x8 a, bf16x8 b, f32x4 c) {
  return __builtin_amdgcn_mfma_f32_16x16x32_bf16(a, b, c, 0, 0, 0);
}

// ---- prep: W transpose (blocks 0..63); per-batch mask prescale+prune (64..71) ----
// Pruning: tile t of batch b can influence softmax only if
//   tilemin_mask[t] < running_min + 1.45e-6   (sound bound, |0.18*qk|<=1000)
// proc[b*33]: count, +1..: tile list; proc[512+b*32+tl]: per-tile need flag.
__global__ __launch_bounds__(256) void prep_w(
    const float* __restrict__ wq, const float* __restrict__ wk,
    const float* __restrict__ wv, const float* __restrict__ wo,
    const float* __restrict__ mask,
    unsigned short* __restrict__ wt, float* __restrict__ mprep,
    int* __restrict__ proc) {
  const int t = threadIdx.x;
  if (blockIdx.x < 64) {
    __shared__ float T[64 * 65];
    const int mat = blockIdx.x >> 4, tn = (blockIdx.x >> 2) & 3, tk = blockIdx.x & 3;
    const int n0 = tn * 64, k0 = tk * 64;
    const float* W = (mat == 0) ? wq : (mat == 1) ? wk : (mat == 2) ? wv : wo;
    const int r0 = t >> 4, c = (t & 15) * 4;
#pragma unroll
    for (int i = 0; i < 4; ++i) {
      int rr = r0 + i * 16;                       // k-local row
      f32x4 x = *(const f32x4*)(W + (k0 + rr) * 256 + n0 + c);
#pragma unroll
      for (int j = 0; j < 4; ++j) T[(c + j) * 65 + rr] = x[j];
    }
    __syncthreads();
#pragma unroll
    for (int i = 0; i < 2; ++i) {
      int u = t + i * 256;
      int n = u >> 3, seg = u & 7;
      us8 pk;
#pragma unroll
      for (int j = 0; j < 8; ++j) pk[j] = f2bf(T[n * 65 + seg * 8 + j]);
      *(us8*)(&wt[mat * 65536 + (n0 + n) * 256 + k0 + seg * 8]) = pk;
    }
  } else {
    __shared__ float tm[32];
    const int b = blockIdx.x - 64;
    const float* mr = mask + b * 2048;
    f32x4 x0 = *(const f32x4*)(mr + t * 8);
    f32x4 x1 = *(const f32x4*)(mr + t * 8 + 4);
    *(f32x4*)(mprep + b * 2048 + t * 8)     = x0 * -1.442695041e9f;
    *(f32x4*)(mprep + b * 2048 + t * 8 + 4) = x1 * -1.442695041e9f;
    float mn = fminf(fminf(fminf(x0[0], x0[1]), fminf(x0[2], x0[3])),
                     fminf(fminf(x1[0], x1[1]), fminf(x1[2], x1[3])));
    mn = fminf(mn, __shfl_xor(mn, 1));
    mn = fminf(mn, __shfl_xor(mn, 2));
    mn = fminf(mn, __shfl_xor(mn, 4));
    if ((t & 7) == 0) tm[t >> 3] = mn;
    __syncthreads();
    if (t == 0) {
      int base = b * 33, cnt = 0;
      float minm = 1e30f;
      for (int tl = 0; tl < 32; ++tl) {
        float v = tm[tl];
        int need = (v < minm + 1.45e-6f) ? 1 : 0;
        proc[512 + b * 32 + tl] = need;
        if (need) { proc[base + 1 + cnt] = tl; ++cnt; }
        minm = fminf(minm, v);
      }
      proc[base] = cnt;
    }
  }
}

// ---- QKV projection: SINGLE-PHASE. Full K=256 in LDS (A 32KB + B 128KB = 160KB),
// one barrier, 64 MFMA/wave straight through. K/V pruned blocks early-exit. ----
__global__ __launch_bounds__(512) void gemm_qkv(
    const float* __restrict__ Aq, const float* __restrict__ Ak, const float* __restrict__ Av,
    const float* __restrict__ bq, const float* __restrict__ bk, const float* __restrict__ bv,
    const unsigned short* __restrict__ wt, const int* __restrict__ proc,
    unsigned short* __restrict__ Qh, unsigned short* __restrict__ Kh,
    unsigned short* __restrict__ VhT) {
  const int p = blockIdx.y;
  if (p != 0 && proc[512 + blockIdx.x] == 0) return;   // block-uniform, pre-barrier

  __shared__ __align__(16) unsigned short At[64 * 256];     // 32 KB
  __shared__ __align__(16) unsigned short Bt[256 * 256];    // 128 KB
  const float* A    = (p == 0) ? Aq : (p == 1) ? Ak : Av;
  const float* bias = (p == 0) ? bq : (p == 1) ? bk : bv;
  const unsigned short* WT = wt + p * 65536;
  const int t = threadIdx.x, lane = t & 63, wvi = t >> 6;   // 8 waves
  const int lr = lane & 15, lg = lane >> 4;
  const int lx = lr & 7;
  const int m0 = blockIdx.x * 64;

  // stage B: 256 rows x 32 us8-units, pre-swizzled global source
#pragma unroll
  for (int i = 0; i < 16; ++i) {
    int u = t + i * 512;
    int row = u >> 5, un = u & 31;
    int g = (un & 24) | ((un & 7) ^ (row & 7));
    gl2lds16(WT + row * 256 + g * 8, &Bt[u * 8]);
  }
  // stage A: f32 -> bf16 via regs, swizzled LDS write
#pragma unroll
  for (int i = 0; i < 4; ++i) {
    int u = t + i * 512;
    int row = u >> 5, un = u & 31;
    const float* src = A + (m0 + row) * 256 + un * 8;
    f32x4 x0 = *(const f32x4*)src;
    f32x4 x1 = *(const f32x4*)(src + 4);
    us8 pk;
#pragma unroll
    for (int j = 0; j < 4; ++j) { pk[j] = f2bf(x0[j]); pk[j + 4] = f2bf(x1[j]); }
    *(us8*)(&At[row * 256 + (((un & 24) | ((un & 7) ^ (row & 7))) << 3)]) = pk;
  }
  __syncthreads();

  f32x4 acc[4][2] = {};
#pragma unroll
  for (int ds = 0; ds < 8; ++ds) {
    const int ku = ds * 4 + lg;
    const int phys = ((ku & 24) | ((ku & 7) ^ lx)) << 3;
    bf16x8 af[4], bfr[2];
#pragma unroll
    for (int m = 0; m < 4; ++m)
      af[m] = *(const bf16x8*)(&At[(m * 16 + lr) * 256 + phys]);
#pragma unroll
    for (int n = 0; n < 2; ++n)
      bfr[n] = *(const bf16x8*)(&Bt[(wvi * 32 + n * 16 + lr) * 256 + phys]);
#pragma unroll
    for (int m = 0; m < 4; ++m)
#pragma unroll
      for (int n = 0; n < 2; ++n)
        acc[m][n] = mfma16(af[m], bfr[n], acc[m][n]);
  }

  const int b = m0 >> 11, s0 = m0 & 2047;
#pragma unroll
  for (int cg = 0; cg < 2; ++cg) {
    int col = wvi * 32 + cg * 16 + lr;
    float bb = bias[col];
    int h = col >> 6, d = col & 63;
    int bh = b * 4 + h;
#pragma unroll
    for (int m = 0; m < 4; ++m) {
      int sb = s0 + m * 16 + lg * 4;
      if (p == 2) {
        us4 o;
#pragma unroll
        for (int r = 0; r < 4; ++r) o[r] = f2bf(acc[m][cg][r] + bb);
        *(us4*)(&VhT[(bh * 64 + d) * 2048 + sb]) = o;
      } else {
        unsigned short* Cp = (p == 0) ? Qh : Kh;
#pragma unroll
        for (int r = 0; r < 4; ++r)
          Cp[(bh * 2048 + sb + r) * 64 + d] = f2bf(acc[m][cg][r] + bb);
      }
    }
  }
}

// ---- FUSED attention + output projection.
// Block = (64 q-rows, batch); 8 waves; waves 2h,2h+1 own head h (32 rows each,
// two 16-row chunks). K/V for all 4 heads staged per tile (64KB, dbuf=128KB).
// Epilogue: O -> swizzled bf16 LDS tile, Wo^T staged into freed dbuf region,
// 64 MFMA/wave, direct f32 stores. LDS total = 160KB.
__global__ __launch_bounds__(512) void attn_out(
    const unsigned short* __restrict__ Qh, const unsigned short* __restrict__ Kh,
    const unsigned short* __restrict__ VhT, const float* __restrict__ mprep,
    const int* __restrict__ proc, const unsigned short* __restrict__ wt,
    const float* __restrict__ bo, float* __restrict__ out) {
  __shared__ __align__(16) unsigned short L[81920];   // 160 KB
  // us-unit offsets: K(buf,h) = buf*16384 + h*4096 ; V(buf,h) = 32768 + same
  // Ao tile (64x256)     at 65536       ; WoT (256x256) at 0 (epilogue reuse)
  const int b = blockIdx.y;
  const int q0 = blockIdx.x * 64;
  const int t = threadIdx.x, lane = t & 63, w = t >> 6;
  const int lr = lane & 15, lg = lane >> 4;
  const int h = w >> 1, ch = w & 1;
  const int bh = b * 4 + h;
  const float* mrow = mprep + b * 2048;
  const int* plist = proc + b * 33;
  const int lx = lr & 7;
  const int lgh = lg >> 1, lgo = (lg & 1) * 4;

  // Q fragments for both 16-row chunks
  bf16x8 qf[2][2];
#pragma unroll
  for (int cc = 0; cc < 2; ++cc)
#pragma unroll
    for (int ds = 0; ds < 2; ++ds)
      qf[cc][ds] = *(const bf16x8*)(Qh + (bh * 2048 + q0 + ch * 32 + cc * 16 + lr) * 64 + ds * 32 + lg * 8);

  f32x4 accO[2][4] = {};
  float mrun[2] = {-3.0e38f, -3.0e38f}, lrun[2] = {0.f, 0.f};

#define STAGE(buf, kv)                                                        \
  {                                                                           \
    _Pragma("unroll")                                                         \
    for (int i = 0; i < 4; ++i) {                                             \
      int u = t + i * 512;                                                    \
      int hh = u >> 9, v = u & 511;                                           \
      int row = v >> 3, g = (v & 7) ^ (row & 7);                              \
      gl2lds16(Kh + ((b * 4 + hh) * 2048 + (kv) + row) * 64 + g * 8,          \
               &L[((buf) * 16384 + hh * 4096 + v * 8)]);                      \
      gl2lds16(VhT + ((b * 4 + hh) * 64 + row) * 2048 + (kv) + g * 8,         \
               &L[(32768 + (buf) * 16384 + hh * 4096 + v * 8)]);              \
    }                                                                         \
  }

  const int cnt = plist[0];                 // block-uniform (per batch)
  STAGE(0, plist[1] * 64)
  __syncthreads();
  int cur = 0;

  for (int j = 0; j < cnt; ++j) {
    const int kv0 = plist[1 + j] * 64;
    if (j + 1 < cnt) STAGE(cur ^ 1, plist[2 + j] * 64)

    const int kb_base = cur * 16384 + h * 4096;
    const int vb_base = 32768 + kb_base;

#pragma unroll
    for (int cc = 0; cc < 2; ++cc) {
      // S^T = K Q^T : accS[kb][r] = S[q][k = kv0 + kb*16 + lg*4 + r]
      f32x4 accS[4] = {};
      __builtin_amdgcn_s_setprio(1);
#pragma unroll
      for (int kb = 0; kb < 4; ++kb)
#pragma unroll
        for (int ds = 0; ds < 2; ++ds) {
          bf16x8 kf = *(const bf16x8*)(&L[kb_base + (((kb * 16 + lr) << 3) | (((ds << 2) | lg) ^ lx)) * 8]);
          accS[kb] = mfma16(kf, qf[cc][ds], accS[kb]);
        }
      __builtin_amdgcn_s_setprio(0);

      f32x4 sv[4];
#pragma unroll
      for (int kb = 0; kb < 4; ++kb) {
        f32x4 mk = *(const f32x4*)(mrow + kv0 + kb * 16 + lg * 4);
        sv[kb] = accS[kb] * 0.1803368801f + mk;
      }
      float mx0 = fmaxf(fmaxf(sv[0][0], sv[0][1]), fmaxf(sv[0][2], sv[0][3]));
      float mx1 = fmaxf(fmaxf(sv[1][0], sv[1][1]), fmaxf(sv[1][2], sv[1][3]));
      float mx2 = fmaxf(fmaxf(sv[2][0], sv[2][1]), fmaxf(sv[2][2], sv[2][3]));
      float mx3 = fmaxf(fmaxf(sv[3][0], sv[3][1]), fmaxf(sv[3][2], sv[3][3]));
      float mx = fmaxf(fmaxf(mx0, mx1), fmaxf(mx2, mx3));
      mx = fmaxf(mx, __shfl_xor(mx, 16));
      mx = fmaxf(mx, __shfl_xor(mx, 32));
      float mnew = fmaxf(mrun[cc], mx);
      float al = __builtin_amdgcn_exp2f(mrun[cc] - mnew);
      mrun[cc] = mnew;

      float px[4][4];
      float lsum = 0.f;
#pragma unroll
      for (int kb = 0; kb < 4; ++kb) {
        float s = 0.f;
#pragma unroll
        for (int r = 0; r < 4; ++r) {
          px[kb][r] = __builtin_amdgcn_exp2f(sv[kb][r] - mnew);
          s += px[kb][r];
        }
        lsum += s;
      }
      lsum += __shfl_xor(lsum, 16);
      lsum += __shfl_xor(lsum, 32);
      lrun[cc] = lrun[cc] * al + lsum;
#pragma unroll
      for (int db = 0; db < 4; ++db) accO[cc][db] *= al;

      bf16x8 pf[2];
#pragma unroll
      for (int ks = 0; ks < 2; ++ks) {
        bf16x8 p;
#pragma unroll
        for (int r = 0; r < 4; ++r) {
          p[r]     = (bf16_t)px[2 * ks][r];
          p[r + 4] = (bf16_t)px[2 * ks + 1][r];
        }
        pf[ks] = p;
      }

      __builtin_amdgcn_s_setprio(1);
#pragma unroll
      for (int ks = 0; ks < 2; ++ks)
#pragma unroll
        for (int db = 0; db < 4; ++db) {
          int row = db * 16 + lr;
          int u0 = (row << 3) | (((ks << 2) | lgh) ^ lx);
          int u1 = (row << 3) | (((ks << 2) | 2 | lgh) ^ lx);
          bf16x4 v0 = *(const bf16x4*)(&L[vb_base + u0 * 8 + lgo]);
          bf16x4 v1 = *(const bf16x4*)(&L[vb_base + u1 * 8 + lgo]);
          bf16x8 vf = __builtin_shufflevector(v0, v1, 0, 1, 2, 3, 4, 5, 6, 7);
          accO[cc][db] = mfma16(vf, pf[ks], accO[cc][db]);
        }
      __builtin_amdgcn_s_setprio(0);
    }

    __syncthreads();   // drains prefetch vmcnt + releases cur buf
    cur ^= 1;
  }
#undef STAGE

  // ---- epilogue: O -> LDS bf16 (swizzled), stage WoT, out = O @ Wo + bo ----
#pragma unroll
  for (int cc = 0; cc < 2; ++cc) {
    const float inv = __builtin_amdgcn_rcpf(lrun[cc]);
    const int row = ch * 32 + cc * 16 + lr;
#pragma unroll
    for (int db = 0; db < 4; ++db) {
      us4 o;
#pragma unroll
      for (int r = 0; r < 4; ++r) o[r] = f2bf(accO[cc][db][r] * inv);
      int un = h * 8 + db * 2 + (lg >> 1);
      int phys = (un & 24) | ((un & 7) ^ (row & 7));
      *(us4*)(&L[65536 + row * 256 + phys * 8 + (lg & 1) * 4]) = o;
    }
  }
  __syncthreads();

  const unsigned short* WT = wt + 3 * 65536;
#pragma unroll
  for (int i = 0; i < 16; ++i) {
    int u = t + i * 512;
    int row = u >> 5, un = u & 31;
    int g = (un & 24) | ((un & 7) ^ (row & 7));
    gl2lds16(WT + row * 256 + g * 8, &L[u * 8]);
  }
  __syncthreads();

  f32x4 acc[4][2] = {};
#pragma unroll
  for (int ds = 0; ds < 8; ++ds) {
    const int ku = ds * 4 + lg;
    const int phys = ((ku & 24) | ((ku & 7) ^ lx)) << 3;
    bf16x8 af[4], bfr[2];
#pragma unroll
    for (int m = 0; m < 4; ++m)
      af[m] = *(const bf16x8*)(&L[65536 + (m * 16 + lr) * 256 + phys]);
#pragma unroll
    for (int n = 0; n < 2; ++n)
      bfr[n] = *(const bf16x8*)(&L[(w * 32 + n * 16 + lr) * 256 + phys]);
#pragma unroll
    for (int m = 0; m < 4; ++m)
#pragma unroll
      for (int n = 0; n < 2; ++n)
        acc[m][n] = mfma16(af[m], bfr[n], acc[m][n]);
  }

#pragma unroll
  for (int cg = 0; cg < 2; ++cg) {
    int col = w * 32 + cg * 16 + lr;
    float bb = bo[col];
#pragma unroll
    for (int m = 0; m < 4; ++m) {
      int rowg = b * 2048 + q0 + m * 16 + lg * 4;
#pragma unroll
      for (int r = 0; r < 4; ++r)
        out[(rowg + r) * 256 + col] = acc[m][cg][r] + bb;
    }
  }
}

extern "C" void kernel_launch(void* const* d_in, const int* in_sizes, int n_in,
                              void* d_out, int out_size, void* d_ws, size_t ws_size,
                              hipStream_t stream) {
  const float* v    = (const float*)d_in[0];
  const float* k    = (const float*)d_in[1];
  const float* q    = (const float*)d_in[2];
  const float* mask = (const float*)d_in[3];
  const float* wq   = (const float*)d_in[4];
  const float* bq   = (const float*)d_in[5];
  const float* wk   = (const float*)d_in[6];
  const float* bk   = (const float*)d_in[7];
  const float* wv   = (const float*)d_in[8];
  const float* bv   = (const float*)d_in[9];
  const float* wo   = (const float*)d_in[10];
  const float* bo   = (const float*)d_in[11];
  float* out = (float*)d_out;
  char* ws = (char*)d_ws;

  // ws: wt 524288 | mprep 65536 | proc 4096 | Qh | Kh | VhT (8 MB each)
  unsigned short* wt  = (unsigned short*)(ws);
  float*          mp  = (float*)(ws + 524288);
  int*            pr  = (int*)(ws + 589824);
  unsigned short* Qh  = (unsigned short*)(ws + 593920);
  unsigned short* Kh  = (unsigned short*)(ws + 593920 + 8388608);
  unsigned short* VhT = (unsigned short*)(ws + 593920 + 2 * 8388608);

  prep_w<<<dim3(72), dim3(256), 0, stream>>>(wq, wk, wv, wo, mask, wt, mp, pr);
  gemm_qkv<<<dim3(256, 3), dim3(512), 0, stream>>>(q, k, v, bq, bk, bv, wt, pr, Qh, Kh, VhT);
  attn_out<<<dim3(32, 8), dim3(512), 0, stream>>>(Qh, Kh, VhT, mp, pr, wt, bo, out);
}

// Round 14
// 54.512 us; speedup vs baseline: 1.0610x; 1.0610x over previous
//
#include <hip/hip_runtime.h>

#define DEV __device__ __forceinline__

typedef __attribute__((ext_vector_type(4))) float f32x4;
typedef __bf16 bf16_t;
typedef __attribute__((ext_vector_type(4))) bf16_t bf16x4;
typedef __attribute__((ext_vector_type(8))) bf16_t bf16x8;
typedef __attribute__((ext_vector_type(8))) unsigned short us8;
typedef __attribute__((ext_vector_type(4))) unsigned short us4;

// B=8, S=2048, D_MODEL=256, H=4, DEPTH=64, BH=32, M=B*S=16384

DEV unsigned short f2bf(float f) {
  bf16_t h = (bf16_t)f;
  return __builtin_bit_cast(unsigned short, h);
}

DEV void gl2lds16(const void* g, void* l) {
  __builtin_amdgcn_global_load_lds(
      (const __attribute__((address_space(1))) unsigned int*)g,
      (__attribute__((address_space(3))) unsigned int*)l, 16, 0, 0);
}

DEV f32x4 mfma16(bf16x8 a, bf16x8 b, f32x4 c) {
  return __builtin_amdgcn_mfma_f32_16x16x32_bf16(a, b, c, 0, 0, 0);
}

// ---- prep: W transpose (blocks 0..63); per-batch mask prescale+prune (64..71) ----
// Pruning: tile t of batch b can influence softmax only if
//   tilemin_mask[t] < running_min + 1.45e-6   (sound bound, |0.18*qk|<=1000)
// proc[b*33]: count, +1..: tile list; proc[512+b*32+tl]: per-tile need flag.
__global__ __launch_bounds__(256) void prep_w(
    const float* __restrict__ wq, const float* __restrict__ wk,
    const float* __restrict__ wv, const float* __restrict__ wo,
    const float* __restrict__ mask,
    unsigned short* __restrict__ wt, float* __restrict__ mprep,
    int* __restrict__ proc) {
  const int t = threadIdx.x;
  if (blockIdx.x < 64) {
    __shared__ float T[64 * 65];
    const int mat = blockIdx.x >> 4, tn = (blockIdx.x >> 2) & 3, tk = blockIdx.x & 3;
    const int n0 = tn * 64, k0 = tk * 64;
    const float* W = (mat == 0) ? wq : (mat == 1) ? wk : (mat == 2) ? wv : wo;
    const int r0 = t >> 4, c = (t & 15) * 4;
#pragma unroll
    for (int i = 0; i < 4; ++i) {
      int rr = r0 + i * 16;                       // k-local row
      f32x4 x = *(const f32x4*)(W + (k0 + rr) * 256 + n0 + c);
#pragma unroll
      for (int j = 0; j < 4; ++j) T[(c + j) * 65 + rr] = x[j];
    }
    __syncthreads();
#pragma unroll
    for (int i = 0; i < 2; ++i) {
      int u = t + i * 256;
      int n = u >> 3, seg = u & 7;
      us8 pk;
#pragma unroll
      for (int j = 0; j < 8; ++j) pk[j] = f2bf(T[n * 65 + seg * 8 + j]);
      *(us8*)(&wt[mat * 65536 + (n0 + n) * 256 + k0 + seg * 8]) = pk;
    }
  } else {
    __shared__ float tm[32];
    const int b = blockIdx.x - 64;
    const float* mr = mask + b * 2048;
    f32x4 x0 = *(const f32x4*)(mr + t * 8);
    f32x4 x1 = *(const f32x4*)(mr + t * 8 + 4);
    *(f32x4*)(mprep + b * 2048 + t * 8)     = x0 * -1.442695041e9f;
    *(f32x4*)(mprep + b * 2048 + t * 8 + 4) = x1 * -1.442695041e9f;
    float mn = fminf(fminf(fminf(x0[0], x0[1]), fminf(x0[2], x0[3])),
                     fminf(fminf(x1[0], x1[1]), fminf(x1[2], x1[3])));
    mn = fminf(mn, __shfl_xor(mn, 1));
    mn = fminf(mn, __shfl_xor(mn, 2));
    mn = fminf(mn, __shfl_xor(mn, 4));
    if ((t & 7) == 0) tm[t >> 3] = mn;
    __syncthreads();
    if (t == 0) {
      int base = b * 33, cnt = 0;
      float minm = 1e30f;
      for (int tl = 0; tl < 32; ++tl) {
        float v = tm[tl];
        int need = (v < minm + 1.45e-6f) ? 1 : 0;
        proc[512 + b * 32 + tl] = need;
        if (need) { proc[base + 1 + cnt] = tl; ++cnt; }
        minm = fminf(minm, v);
      }
      proc[base] = cnt;
    }
  }
}

// ---- QKV projection: SMALL-BLOCK HIGH-OCCUPANCY. Tile M32 x N256(full) x BK64,
// 256 threads / 4 waves (wave = one head's 64 cols), LDS 36KB -> 4 blocks/CU.
// A read exactly once; simple 2-barrier K-loop; TLP across ~6 blocks/CU hides
// stage latency. K/V pruned strips early-exit. ----
__global__ __launch_bounds__(256, 4) void gemm_qkv(
    const float* __restrict__ Aq, const float* __restrict__ Ak, const float* __restrict__ Av,
    const float* __restrict__ bq, const float* __restrict__ bk, const float* __restrict__ bv,
    const unsigned short* __restrict__ wt, const int* __restrict__ proc,
    unsigned short* __restrict__ Qh, unsigned short* __restrict__ Kh,
    unsigned short* __restrict__ VhT) {
  const int p = blockIdx.y;
  // strip -> (batch, 64-row tile): b = bid>>6, tile = (bid>>1)&31
  if (p != 0 && proc[512 + ((blockIdx.x >> 6) << 5) + ((blockIdx.x >> 1) & 31)] == 0) return;

  __shared__ __align__(16) unsigned short At[32 * 64];      // 4 KB
  __shared__ __align__(16) unsigned short Bt[256 * 64];     // 32 KB
  const float* A    = (p == 0) ? Aq : (p == 1) ? Ak : Av;
  const float* bias = (p == 0) ? bq : (p == 1) ? bk : bv;
  const unsigned short* WT = wt + p * 65536;
  const int t = threadIdx.x, lane = t & 63, w = t >> 6;     // 4 waves
  const int lr = lane & 15, lg = lane >> 4;
  const int lx = lr & 7;
  const int m0 = blockIdx.x * 32;

  // A staging: thread t covers row=t>>3 (0..31), seg=t&7 (8 f32 = 32B)
  const int as_row = t >> 3, as_seg = t & 7;
  const float* agp = A + (m0 + as_row) * 256 + as_seg * 8;

  f32x4 acc[2][4] = {};   // [m][cg]

  for (int j = 0; j < 4; ++j) {
    const int k0 = j * 64;
    // stage B[256][64]: 2048 us8-units, pre-swizzled global source
#pragma unroll
    for (int i = 0; i < 8; ++i) {
      int u = t + i * 256;
      int row = u >> 3, g = (u & 7) ^ (row & 7);
      gl2lds16(WT + row * 256 + k0 + g * 8, &Bt[u * 8]);
    }
    // stage A: f32 -> bf16 via regs, swizzled LDS write
    {
      f32x4 x0 = *(const f32x4*)(agp + k0);
      f32x4 x1 = *(const f32x4*)(agp + k0 + 4);
      us8 pk;
#pragma unroll
      for (int jj = 0; jj < 4; ++jj) { pk[jj] = f2bf(x0[jj]); pk[jj + 4] = f2bf(x1[jj]); }
      *(us8*)(&At[(as_row << 6) + ((as_seg ^ (as_row & 7)) << 3)]) = pk;
    }
    __syncthreads();

#pragma unroll
    for (int ds = 0; ds < 2; ++ds) {
      const int ku = (ds << 2) | lg;
      const int phys = (ku ^ lx) << 3;
      bf16x8 af[2], bfr[4];
#pragma unroll
      for (int m = 0; m < 2; ++m)
        af[m] = *(const bf16x8*)(&At[((m * 16 + lr) << 6) + phys]);
#pragma unroll
      for (int cg = 0; cg < 4; ++cg)
        bfr[cg] = *(const bf16x8*)(&Bt[((w * 64 + cg * 16 + lr) << 6) + phys]);
#pragma unroll
      for (int m = 0; m < 2; ++m)
#pragma unroll
        for (int cg = 0; cg < 4; ++cg)
          acc[m][cg] = mfma16(af[m], bfr[cg], acc[m][cg]);
    }
    __syncthreads();
  }

  const int b = m0 >> 11, s0 = m0 & 2047;
  const int bh = b * 4 + w;            // wave w = head w
#pragma unroll
  for (int cg = 0; cg < 4; ++cg) {
    int d = cg * 16 + lr;
    float bb = bias[w * 64 + d];
#pragma unroll
    for (int m = 0; m < 2; ++m) {
      int sb = s0 + m * 16 + lg * 4;
      if (p == 2) {
        us4 o;
#pragma unroll
        for (int r = 0; r < 4; ++r) o[r] = f2bf(acc[m][cg][r] + bb);
        *(us4*)(&VhT[(bh * 64 + d) * 2048 + sb]) = o;
      } else {
        unsigned short* Cp = (p == 0) ? Qh : Kh;
#pragma unroll
        for (int r = 0; r < 4; ++r)
          Cp[(bh * 2048 + sb + r) * 64 + d] = f2bf(acc[m][cg][r] + bb);
      }
    }
  }
}

// ---- FUSED attention + output projection (unchanged from round 13). ----
__global__ __launch_bounds__(512) void attn_out(
    const unsigned short* __restrict__ Qh, const unsigned short* __restrict__ Kh,
    const unsigned short* __restrict__ VhT, const float* __restrict__ mprep,
    const int* __restrict__ proc, const unsigned short* __restrict__ wt,
    const float* __restrict__ bo, float* __restrict__ out) {
  __shared__ __align__(16) unsigned short L[81920];   // 160 KB
  const int b = blockIdx.y;
  const int q0 = blockIdx.x * 64;
  const int t = threadIdx.x, lane = t & 63, w = t >> 6;
  const int lr = lane & 15, lg = lane >> 4;
  const int h = w >> 1, ch = w & 1;
  const int bh = b * 4 + h;
  const float* mrow = mprep + b * 2048;
  const int* plist = proc + b * 33;
  const int lx = lr & 7;
  const int lgh = lg >> 1, lgo = (lg & 1) * 4;

  bf16x8 qf[2][2];
#pragma unroll
  for (int cc = 0; cc < 2; ++cc)
#pragma unroll
    for (int ds = 0; ds < 2; ++ds)
      qf[cc][ds] = *(const bf16x8*)(Qh + (bh * 2048 + q0 + ch * 32 + cc * 16 + lr) * 64 + ds * 32 + lg * 8);

  f32x4 accO[2][4] = {};
  float mrun[2] = {-3.0e38f, -3.0e38f}, lrun[2] = {0.f, 0.f};

#define STAGE(buf, kv)                                                        \
  {                                                                           \
    _Pragma("unroll")                                                         \
    for (int i = 0; i < 4; ++i) {                                             \
      int u = t + i * 512;                                                    \
      int hh = u >> 9, v = u & 511;                                           \
      int row = v >> 3, g = (v & 7) ^ (row & 7);                              \
      gl2lds16(Kh + ((b * 4 + hh) * 2048 + (kv) + row) * 64 + g * 8,          \
               &L[((buf) * 16384 + hh * 4096 + v * 8)]);                      \
      gl2lds16(VhT + ((b * 4 + hh) * 64 + row) * 2048 + (kv) + g * 8,         \
               &L[(32768 + (buf) * 16384 + hh * 4096 + v * 8)]);              \
    }                                                                         \
  }

  const int cnt = plist[0];                 // block-uniform (per batch)
  STAGE(0, plist[1] * 64)
  __syncthreads();
  int cur = 0;

  for (int j = 0; j < cnt; ++j) {
    const int kv0 = plist[1 + j] * 64;
    if (j + 1 < cnt) STAGE(cur ^ 1, plist[2 + j] * 64)

    const int kb_base = cur * 16384 + h * 4096;
    const int vb_base = 32768 + kb_base;

#pragma unroll
    for (int cc = 0; cc < 2; ++cc) {
      f32x4 accS[4] = {};
      __builtin_amdgcn_s_setprio(1);
#pragma unroll
      for (int kb = 0; kb < 4; ++kb)
#pragma unroll
        for (int ds = 0; ds < 2; ++ds) {
          bf16x8 kf = *(const bf16x8*)(&L[kb_base + (((kb * 16 + lr) << 3) | (((ds << 2) | lg) ^ lx)) * 8]);
          accS[kb] = mfma16(kf, qf[cc][ds], accS[kb]);
        }
      __builtin_amdgcn_s_setprio(0);

      f32x4 sv[4];
#pragma unroll
      for (int kb = 0; kb < 4; ++kb) {
        f32x4 mk = *(const f32x4*)(mrow + kv0 + kb * 16 + lg * 4);
        sv[kb] = accS[kb] * 0.1803368801f + mk;
      }
      float mx0 = fmaxf(fmaxf(sv[0][0], sv[0][1]), fmaxf(sv[0][2], sv[0][3]));
      float mx1 = fmaxf(fmaxf(sv[1][0], sv[1][1]), fmaxf(sv[1][2], sv[1][3]));
      float mx2 = fmaxf(fmaxf(sv[2][0], sv[2][1]), fmaxf(sv[2][2], sv[2][3]));
      float mx3 = fmaxf(fmaxf(sv[3][0], sv[3][1]), fmaxf(sv[3][2], sv[3][3]));
      float mx = fmaxf(fmaxf(mx0, mx1), fmaxf(mx2, mx3));
      mx = fmaxf(mx, __shfl_xor(mx, 16));
      mx = fmaxf(mx, __shfl_xor(mx, 32));
      float mnew = fmaxf(mrun[cc], mx);
      float al = __builtin_amdgcn_exp2f(mrun[cc] - mnew);
      mrun[cc] = mnew;

      float px[4][4];
      float lsum = 0.f;
#pragma unroll
      for (int kb = 0; kb < 4; ++kb) {
        float s = 0.f;
#pragma unroll
        for (int r = 0; r < 4; ++r) {
          px[kb][r] = __builtin_amdgcn_exp2f(sv[kb][r] - mnew);
          s += px[kb][r];
        }
        lsum += s;
      }
      lsum += __shfl_xor(lsum, 16);
      lsum += __shfl_xor(lsum, 32);
      lrun[cc] = lrun[cc] * al + lsum;
#pragma unroll
      for (int db = 0; db < 4; ++db) accO[cc][db] *= al;

      bf16x8 pf[2];
#pragma unroll
      for (int ks = 0; ks < 2; ++ks) {
        bf16x8 p;
#pragma unroll
        for (int r = 0; r < 4; ++r) {
          p[r]     = (bf16_t)px[2 * ks][r];
          p[r + 4] = (bf16_t)px[2 * ks + 1][r];
        }
        pf[ks] = p;
      }

      __builtin_amdgcn_s_setprio(1);
#pragma unroll
      for (int ks = 0; ks < 2; ++ks)
#pragma unroll
        for (int db = 0; db < 4; ++db) {
          int row = db * 16 + lr;
          int u0 = (row << 3) | (((ks << 2) | lgh) ^ lx);
          int u1 = (row << 3) | (((ks << 2) | 2 | lgh) ^ lx);
          bf16x4 v0 = *(const bf16x4*)(&L[vb_base + u0 * 8 + lgo]);
          bf16x4 v1 = *(const bf16x4*)(&L[vb_base + u1 * 8 + lgo]);
          bf16x8 vf = __builtin_shufflevector(v0, v1, 0, 1, 2, 3, 4, 5, 6, 7);
          accO[cc][db] = mfma16(vf, pf[ks], accO[cc][db]);
        }
      __builtin_amdgcn_s_setprio(0);
    }

    __syncthreads();
    cur ^= 1;
  }
#undef STAGE

  // ---- epilogue: O -> LDS bf16 (swizzled), stage WoT, out = O @ Wo + bo ----
#pragma unroll
  for (int cc = 0; cc < 2; ++cc) {
    const float inv = __builtin_amdgcn_rcpf(lrun[cc]);
    const int row = ch * 32 + cc * 16 + lr;
#pragma unroll
    for (int db = 0; db < 4; ++db) {
      us4 o;
#pragma unroll
      for (int r = 0; r < 4; ++r) o[r] = f2bf(accO[cc][db][r] * inv);
      int un = h * 8 + db * 2 + (lg >> 1);
      int phys = (un & 24) | ((un & 7) ^ (row & 7));
      *(us4*)(&L[65536 + row * 256 + phys * 8 + (lg & 1) * 4]) = o;
    }
  }
  __syncthreads();

  const unsigned short* WT = wt + 3 * 65536;
#pragma unroll
  for (int i = 0; i < 16; ++i) {
    int u = t + i * 512;
    int row = u >> 5, un = u & 31;
    int g = (un & 24) | ((un & 7) ^ (row & 7));
    gl2lds16(WT + row * 256 + g * 8, &L[u * 8]);
  }
  __syncthreads();

  f32x4 acc[4][2] = {};
#pragma unroll
  for (int ds = 0; ds < 8; ++ds) {
    const int ku = ds * 4 + lg;
    const int phys = ((ku & 24) | ((ku & 7) ^ lx)) << 3;
    bf16x8 af[4], bfr[2];
#pragma unroll
    for (int m = 0; m < 4; ++m)
      af[m] = *(const bf16x8*)(&L[65536 + (m * 16 + lr) * 256 + phys]);
#pragma unroll
    for (int n = 0; n < 2; ++n)
      bfr[n] = *(const bf16x8*)(&L[(w * 32 + n * 16 + lr) * 256 + phys]);
#pragma unroll
    for (int m = 0; m < 4; ++m)
#pragma unroll
      for (int n = 0; n < 2; ++n)
        acc[m][n] = mfma16(af[m], bfr[n], acc[m][n]);
  }

#pragma unroll
  for (int cg = 0; cg < 2; ++cg) {
    int col = w * 32 + cg * 16 + lr;
    float bb = bo[col];
#pragma unroll
    for (int m = 0; m < 4; ++m) {
      int rowg = b * 2048 + q0 + m * 16 + lg * 4;
#pragma unroll
      for (int r = 0; r < 4; ++r)
        out[(rowg + r) * 256 + col] = acc[m][cg][r] + bb;
    }
  }
}

extern "C" void kernel_launch(void* const* d_in, const int* in_sizes, int n_in,
                              void* d_out, int out_size, void* d_ws, size_t ws_size,
                              hipStream_t stream) {
  const float* v    = (const float*)d_in[0];
  const float* k    = (const float*)d_in[1];
  const float* q    = (const float*)d_in[2];
  const float* mask = (const float*)d_in[3];
  const float* wq   = (const float*)d_in[4];
  const float* bq   = (const float*)d_in[5];
  const float* wk   = (const float*)d_in[6];
  const float* bk   = (const float*)d_in[7];
  const float* wv   = (const float*)d_in[8];
  const float* bv   = (const float*)d_in[9];
  const float* wo   = (const float*)d_in[10];
  const float* bo   = (const float*)d_in[11];
  float* out = (float*)d_out;
  char* ws = (char*)d_ws;

  // ws: wt 524288 | mprep 65536 | proc 4096 | Qh | Kh | VhT (8 MB each)
  unsigned short* wt  = (unsigned short*)(ws);
  float*          mp  = (float*)(ws + 524288);
  int*            pr  = (int*)(ws + 589824);
  unsigned short* Qh  = (unsigned short*)(ws + 593920);
  unsigned short* Kh  = (unsigned short*)(ws + 593920 + 8388608);
  unsigned short* VhT = (unsigned short*)(ws + 593920 + 2 * 8388608);

  prep_w<<<dim3(72), dim3(256), 0, stream>>>(wq, wk, wv, wo, mask, wt, mp, pr);
  gemm_qkv<<<dim3(512, 3), dim3(256), 0, stream>>>(q, k, v, bq, bk, bv, wt, pr, Qh, Kh, VhT);
  attn_out<<<dim3(32, 8), dim3(512), 0, stream>>>(Qh, Kh, VhT, mp, pr, wt, bo, out);
}